// Round 10
// baseline (207.635 us; speedup 1.0000x reference)
//
#include <hip/hip_runtime.h>
#include <hip/hip_bf16.h>
#include <math.h>

#define NB 8
#define NS 1024
#define NT 1024
#define NE 256
#define NHEADS 8
#define DH 32
#define LOG2E 1.4426950408889634f

typedef __attribute__((ext_vector_type(8))) short short8;
typedef __attribute__((ext_vector_type(8))) unsigned short ushort8;
typedef __attribute__((ext_vector_type(4))) float f32x4;

// ws layout (byte offsets), ~27.7 MB total
#define O_V     0x0000000u   // f32 [b][h][t][d]              8 MB
#define O_T1    0x0800000u   // f32 [64][1025][32] suffix     8.4 MB
#define O_T2    0x1010000u   // f32 [64][1025][32] prefix     8.4 MB
#define O_EST1  0x1820000u   // f32 [64][1024]  e^{st'}       256 KB
#define O_EST2  0x1860000u   // f32 [64][1024]  e^{0.2 st'}   256 KB
#define O_RF    0x18A0000u   // float4 [64][1024] {v1,v2,thr,k} 1 MB
#define O_WTT   0x19A0000u   // bf16 [256][256] W_trg^T
#define O_WTO   0x19C0000u   // bf16 [256][256] W_out^T
#define O_CSRC  0x19E0000u   // f32 [8][256]
#define O_CTRG  0x19E2000u
#define O_SSRC  0x19E4000u   // f32 [8192][8]
#define O_STRG  0x1A24000u
#define O_FLAG  0x1A64000u

__device__ __forceinline__ unsigned short f2bf(float f) {
    __hip_bfloat16 h = __float2bfloat16(f);
    union { __hip_bfloat16 h; unsigned short u; } c; c.h = h;
    return c.u;
}
// raw v_exp_f32 (= exp2); inputs pre-scaled by LOG2E
__device__ __forceinline__ float exp2_fast(float x) {
    float r;
    asm("v_exp_f32 %0, %1" : "=v"(r) : "v"(x));
    return r;
}

// ---------------------------------------------------------------------------
// K1 setup: bid0 = mask probe; bid1/2 = c_src/c_trg; bid3..34 = W transposes.
// ---------------------------------------------------------------------------
__global__ __launch_bounds__(256) void setup_kernel(
    const unsigned* __restrict__ tmask_dw, const float* __restrict__ Wsrc,
    const float* __restrict__ Wtrg, const float* __restrict__ Wout,
    const float* __restrict__ asrc, const float* __restrict__ atrg,
    float* __restrict__ c_src, float* __restrict__ c_trg,
    unsigned short* __restrict__ Wt_t, unsigned short* __restrict__ Wt_o,
    int* __restrict__ flag) {
    __shared__ __align__(16) char sm[16640];
    const int tid = threadIdx.x;
    const int bid = blockIdx.x;

    if (bid == 0) {
        __shared__ int s_ok;
        if (tid == 0) s_ok = 1;
        __syncthreads();
        for (int i = tid; i < 2048; i += 256)
            if (tmask_dw[i] > 1u) s_ok = 0;
        __syncthreads();
        if (tid == 0) *flag = s_ok;
    } else if (bid <= 2) {
        float* a_sh = (float*)sm;
        const float* W = (bid == 1) ? Wsrc : Wtrg;
        const float* a = (bid == 1) ? asrc : atrg;
        float* c = (bid == 1) ? c_src : c_trg;
        a_sh[tid] = a[tid];
        __syncthreads();
        const int e = tid;
        float ch[8];
#pragma unroll
        for (int h = 0; h < 8; ++h) ch[h] = 0.f;
        for (int i = 0; i < 64; ++i) {
            const float4 wv = *(const float4*)&W[(size_t)e * NE + i * 4];
            const int h = i >> 3, d0 = (i & 7) * 4;
            ch[h] += wv.x * a_sh[h * 32 + d0] + wv.y * a_sh[h * 32 + d0 + 1] +
                     wv.z * a_sh[h * 32 + d0 + 2] + wv.w * a_sh[h * 32 + d0 + 3];
        }
#pragma unroll
        for (int h = 0; h < 8; ++h) c[h * NE + e] = ch[h];
    } else {
        const int q = bid - 3;
        const float* W = (q >> 4) ? Wout : Wtrg;
        unsigned short* Wt = (q >> 4) ? Wt_o : Wt_t;
        const int tl = q & 15;
        const int k0 = (tl >> 2) * 64, n0 = (tl & 3) * 64;
        float* xs = (float*)sm;                   // [64][65]
#pragma unroll
        for (int it = 0; it < 4; ++it) {
            const int slot = it * 256 + tid;
            const int k = slot >> 4, c4 = slot & 15;
            const float4 v = *(const float4*)&W[(size_t)(k0 + k) * NE + n0 + c4 * 4];
            float* p = &xs[k * 65 + c4 * 4];
            p[0] = v.x; p[1] = v.y; p[2] = v.z; p[3] = v.w;
        }
        __syncthreads();
#pragma unroll
        for (int it = 0; it < 2; ++it) {
            const int slot = it * 256 + tid;
            const int n = slot >> 3, kc = slot & 7;
            ushort8 v;
#pragma unroll
            for (int e = 0; e < 8; ++e)
                v[e] = f2bf(xs[(kc * 8 + e) * 65 + n]);
            *(ushort8*)&Wt[(size_t)(n0 + n) * NE + k0 + kc * 8] = v;
        }
    }
}

// ---------------------------------------------------------------------------
// K2 mid: bid<256 -> V gemm (trg @ W_trg, bf16 MFMA), writes V f32 [b][h][t][d];
// bid>=256 -> score rows (src@c_src / trg@c_trg), exact f32.
// ---------------------------------------------------------------------------
__global__ __launch_bounds__(256) void mid_kernel(
    const float* __restrict__ src, const float* __restrict__ trg,
    const float* __restrict__ c_src, const float* __restrict__ c_trg,
    const unsigned short* __restrict__ Wt_t, float* __restrict__ Vg,
    float* __restrict__ ssrc, float* __restrict__ strg) {
    __shared__ __align__(16) char sm[40960];
    const int tid = threadIdx.x;
    const int bid = blockIdx.x;

    if (bid < 256) {
        unsigned short* As = (unsigned short*)sm;            // [64][256] bf16
        const int lane = tid & 63, w = tid >> 6;
        const int row0 = (bid >> 1) * 64;
        const int col0 = (bid & 1) * 128;

#pragma unroll
        for (int it = 0; it < 8; ++it) {
            const int gf = it * 256 + tid;
            const int row = gf >> 5, g3 = gf & 31;
            const float4 a = *(const float4*)&trg[(size_t)(row0 + row) * NE + g3 * 8];
            const float4 b = *(const float4*)&trg[(size_t)(row0 + row) * NE + g3 * 8 + 4];
            ushort8 v;
            v[0] = f2bf(a.x); v[1] = f2bf(a.y); v[2] = f2bf(a.z); v[3] = f2bf(a.w);
            v[4] = f2bf(b.x); v[5] = f2bf(b.y); v[6] = f2bf(b.z); v[7] = f2bf(b.w);
            *(ushort8*)&As[row * NE + ((g3 ^ (row & 7)) * 8)] = v;
        }
        __syncthreads();

        const int r = lane & 15, g = lane >> 4;
        short8 af[8];
#pragma unroll
        for (int kk = 0; kk < 8; ++kk)
            af[kk] = *(const short8*)&As[(w * 16 + r) * NE + (((kk * 4 + g) ^ (r & 7)) * 8)];

        f32x4 acc[8];
#pragma unroll
        for (int nt = 0; nt < 8; ++nt) acc[nt] = (f32x4){0.f, 0.f, 0.f, 0.f};
#pragma unroll
        for (int kk = 0; kk < 8; ++kk) {
#pragma unroll
            for (int nt = 0; nt < 8; ++nt) {
                const int col = col0 + nt * 16 + r;
                const short8 bf = *(const short8*)&Wt_t[(size_t)col * NE + kk * 32 + g * 8];
                acc[nt] = __builtin_amdgcn_mfma_f32_16x16x32_bf16(af[kk], bf, acc[nt], 0, 0, 0);
            }
        }

        // direct store: V[((b*8+h)*1024 + t)*32 + d] f32
        const int b = row0 >> 10;
        const int tloc = (row0 & 1023) + w * 16 + g * 4;
#pragma unroll
        for (int nt = 0; nt < 8; ++nt) {
            const int col = col0 + nt * 16 + r;
            const int h = col >> 5, d = col & 31;
            float* vb = Vg + ((size_t)(b * 8 + h) * 1024 + tloc) * 32 + d;
#pragma unroll
            for (int j = 0; j < 4; ++j)
                vb[(size_t)j * 32] = acc[nt][j];
        }
    } else {
        float* xs = (float*)sm;                  // [32][256]
        float* cs = (float*)(sm + 32768);        // [8][256]
        const int rowg0 = (bid - 256) * 32;
        const bool is_src = rowg0 < NB * NS;
        const float* X = is_src ? (src + (size_t)rowg0 * NE)
                                : (trg + (size_t)(rowg0 - NB * NS) * NE);
        const float* C = is_src ? c_src : c_trg;
        float* S = is_src ? (ssrc + (size_t)rowg0 * NHEADS)
                          : (strg + (size_t)(rowg0 - NB * NS) * NHEADS);

#pragma unroll
        for (int it = 0; it < 8; ++it) {
            const int slot = it * 256 + tid;
            const int row = slot >> 6, c4 = slot & 63;
            *(float4*)&xs[row * NE + c4 * 4] =
                *(const float4*)&X[(size_t)row * NE + c4 * 4];
            cs[slot] = C[slot];
        }
        __syncthreads();

        const int r = tid >> 3, h = tid & 7;
        float s = 0.f;
        for (int e = 0; e < NE; e += 4) {
            const float4 x = *(const float4*)&xs[r * NE + e];
            const float4 c = *(const float4*)&cs[h * NE + e];
            s += x.x * c.x + x.y * c.y + x.z * c.z + x.w * c.w;
        }
        S[(size_t)r * NHEADS + h] = s;
    }
}

// ---------------------------------------------------------------------------
// K3 sortscan: one block per (b,h). Sort st (exp2-domain), build suffix/prefix
// scalar+vector tables, est arrays (orig order), per-row factors {v1,v2,thr,k}.
// ---------------------------------------------------------------------------
__global__ __launch_bounds__(256) void sortscan_kernel(
    const float* __restrict__ ssrc, const float* __restrict__ strg,
    const void* __restrict__ smask, const void* __restrict__ tmask,
    const int* __restrict__ flag_p, const float* __restrict__ Vg,
    float* __restrict__ T1g, float* __restrict__ T2g,
    float* __restrict__ est1g, float* __restrict__ est2g,
    float4* __restrict__ rfg) {
    const int bid = blockIdx.x;          // b*8 + h
    const int b = bid >> 3, h = bid & 7;
    const int tid = threadIdx.x;
    const int lane = tid & 63;
    const int w = tid >> 6;
    const int flag = *flag_p;
    const float INF = __int_as_float(0x7f800000);

    __shared__ float skey[1024];
    __shared__ int   sidx[1024];
    __shared__ float w1[1024], w2[1024];
    __shared__ float sS1[1025], sS2[1025];
    __shared__ float s_redm[4];
    __shared__ int   s_redc[4];
    __shared__ float s_Smax;

    // stage keys (exp2 domain), track local max/count of valid
    float lmax = -INF;
    int lcnt = 0;
    for (int t = tid; t < 1024; t += 256) {
        const bool mv = flag ? (((const int*)tmask)[b * 1024 + t] != 0)
                             : (((const unsigned char*)tmask)[b * 1024 + t] != 0);
        const float S = strg[((size_t)b * 1024 + t) * 8 + h] * LOG2E;
        skey[t] = mv ? S : INF;
        sidx[t] = t;
        if (mv) { lmax = fmaxf(lmax, S); ++lcnt; }
    }
#pragma unroll
    for (int off = 32; off >= 1; off >>= 1) {
        lmax = fmaxf(lmax, __shfl_xor(lmax, off));
        lcnt += __shfl_xor(lcnt, off);
    }
    if (lane == 0) { s_redm[w] = lmax; s_redc[w] = lcnt; }
    __syncthreads();
    if (tid == 0) {
        float m = fmaxf(fmaxf(s_redm[0], s_redm[1]), fmaxf(s_redm[2], s_redm[3]));
        int c = s_redc[0] + s_redc[1] + s_redc[2] + s_redc[3];
        s_Smax = (c > 0) ? m : 0.f;
    }
    __syncthreads();
    const float Smax = s_Smax;

    // bitonic sort ascending (key, idx)
    for (int kk = 2; kk <= 1024; kk <<= 1) {
        for (int jj = kk >> 1; jj > 0; jj >>= 1) {
            __syncthreads();
            for (int ii = tid; ii < 1024; ii += 256) {
                const int pr = ii ^ jj;
                if (pr > ii) {
                    const bool up = ((ii & kk) == 0);
                    const float a = skey[ii], c = skey[pr];
                    if (up ? (a > c) : (a < c)) {
                        skey[ii] = c; skey[pr] = a;
                        const int t = sidx[ii]; sidx[ii] = sidx[pr]; sidx[pr] = t;
                    }
                }
            }
        }
    }
    __syncthreads();

    // sorted-order weights (0 for invalid/INF keys)
    for (int j = tid; j < 1024; j += 256) {
        const float sk = skey[j];
        const bool valid = sk < 1e30f;
        w1[j] = valid ? exp2_fast(sk - Smax) : 0.f;
        w2[j] = valid ? exp2_fast(0.2f * (sk - Smax)) : 0.f;
    }
    __syncthreads();

    if (w == 0) {
        // vector table scans: half0 = T1 suffix, half1 = T2 prefix
        const int hf = lane >> 5, d = lane & 31;
        float* Tb = (hf ? T2g : T1g) + (size_t)bid * 1025 * 32;
        if (!hf) Tb[(size_t)1024 * 32 + d] = 0.f;
        float acc = 0.f;
        for (int j = 0; j < 1024; ++j) {
            const int idx = hf ? j : 1023 - j;
            const int perm = sidx[idx];
            const float wv = hf ? w2[idx] : w1[idx];
            const float vv = Vg[((size_t)bid * 1024 + perm) * 32 + d];
            const float pre = acc;
            acc = fmaf(wv, vv, acc);
            Tb[(size_t)idx * 32 + d] = hf ? pre : acc;
        }
        if (hf) Tb[(size_t)1024 * 32 + d] = acc;
    } else if (w == 1) {
        // scalar scans: half0 = S1 suffix, half1 = S2 prefix
        const int hf = lane >> 5;
        float acc = 0.f;
        if (lane == 0) sS1[1024] = 0.f;
        for (int j = 0; j < 1024; ++j) {
            const int idx = hf ? j : 1023 - j;
            const float wv = hf ? w2[idx] : w1[idx];
            const float pre = acc;
            acc += wv;
            if ((lane & 31) == 0) (hf ? sS2 : sS1)[idx] = hf ? pre : acc;
        }
        if (lane == 32) sS2[1024] = acc;
    } else {
        // est arrays in ORIGINAL t order
        for (int t = tid - 128; t < 1024; t += 128) {
            const bool mv = flag ? (((const int*)tmask)[b * 1024 + t] != 0)
                                 : (((const unsigned char*)tmask)[b * 1024 + t] != 0);
            const float S = strg[((size_t)b * 1024 + t) * 8 + h] * LOG2E;
            est1g[(size_t)bid * 1024 + t] = mv ? exp2_fast(S - Smax) : 0.f;
            est2g[(size_t)bid * 1024 + t] = mv ? exp2_fast(0.2f * (S - Smax)) : 0.f;
        }
    }
    __syncthreads();

    // per-row factors
    for (int s = tid; s < 1024; s += 256) {
        const float SS = ssrc[((size_t)b * 1024 + s) * 8 + h] * LOG2E;
        const bool rowv = flag ? (((const int*)smask)[b * 1024 + s] != 0)
                               : (((const unsigned char*)smask)[b * 1024 + s] != 0);
        const float key = -SS;
        int lo = 0, hi = 1024;
        while (lo < hi) {
            const int mid = (lo + hi) >> 1;
            if (skey[mid] < key) lo = mid + 1; else hi = mid;
        }
        const int k = lo;
        const float SSp = SS + Smax;
        const float e1 = exp2_fast(SSp);
        const float e2 = exp2_fast(0.2f * SSp);
        const float sum = e1 * sS1[k] + e2 * sS2[k];
        const float inv = (rowv && sum > 0.f) ? 1.f / sum : 0.f;
        float4 rf;
        rf.x = e1 * inv;
        rf.y = e2 * inv;
        rf.z = exp2_fast(-SSp);
        rf.w = __int_as_float(k);
        rfg[(size_t)bid * 1024 + s] = rf;
    }
}

// ---------------------------------------------------------------------------
// K4 attn + out: block = (b, 16-row stile). agg from tables -> LDS bf16 ->
// 16x256x256 out-GEMM; attn = sel(est1*v1, est2*v2), coalesced 1KB stores.
// ---------------------------------------------------------------------------
__global__ __launch_bounds__(256) void attnout_kernel(
    const float4* __restrict__ rfg, const float* __restrict__ T1g,
    const float* __restrict__ T2g, const float* __restrict__ est1g,
    const float* __restrict__ est2g, const unsigned short* __restrict__ Wt_o,
    float* __restrict__ attn, float* __restrict__ out) {
    const int blk = blockIdx.x;
    const int q = blk & 63;
    const int b = blk >> 6;
    const int tid = threadIdx.x;
    const int lane = tid & 63;
    const int w = tid >> 6;

    __shared__ float4 s_rf[8][16];
    __shared__ __align__(16) unsigned short agg_sw[16 * 256];

    if (tid < 128) {
        const int h = tid >> 4, r = tid & 15;
        s_rf[h][r] = rfg[(size_t)(b * 8 + h) * 1024 + q * 16 + r];
    }
    __syncthreads();

    // agg from tables: thread (h = tid>>5, d = tid&31) covers 16 rows
    {
        const int h = tid >> 5, d = tid & 31;
        const size_t tb = (size_t)(b * 8 + h) * 1025 * 32 + d;
#pragma unroll
        for (int r = 0; r < 16; ++r) {
            const float4 rf = s_rf[h][r];
            const int k = __float_as_int(rf.w);
            const float a = rf.x * T1g[tb + (size_t)k * 32] +
                            rf.y * T2g[tb + (size_t)k * 32];
            const int col = h * 32 + d;
            agg_sw[r * 256 + ((((col >> 3) ^ (r & 7)) << 3) | (col & 7))] = f2bf(a);
        }
    }
    __syncthreads();

    // out-GEMM: 16 rows x 256 cols, K=256; wave w owns cols [w*64, w*64+64)
    const int r = lane & 15, g = lane >> 4;
    f32x4 oacc[4];
#pragma unroll
    for (int nt = 0; nt < 4; ++nt) oacc[nt] = (f32x4){0.f, 0.f, 0.f, 0.f};
#pragma unroll
    for (int kk = 0; kk < 8; ++kk) {
        const short8 af = *(const short8*)&agg_sw[r * 256 + (((kk * 4 + g) ^ (r & 7)) * 8)];
#pragma unroll
        for (int nt = 0; nt < 4; ++nt) {
            const int col = w * 64 + nt * 16 + r;
            const short8 bf = *(const short8*)&Wt_o[(size_t)col * NE + kk * 32 + g * 8];
            oacc[nt] = __builtin_amdgcn_mfma_f32_16x16x32_bf16(af, bf, oacc[nt], 0, 0, 0);
        }
    }
#pragma unroll
    for (int nt = 0; nt < 4; ++nt) {
        const int col = w * 64 + nt * 16 + r;
#pragma unroll
        for (int j = 0; j < 4; ++j)
            out[((size_t)b * NS + q * 16 + g * 4 + j) * NE + col] = oacc[nt][j];
    }

    // attn stores: 32 (head,row) pairs per wave, 1KB contiguous per inst
    for (int i = 0; i < 32; ++i) {
        const int idx = w * 32 + i;
        const int h = idx >> 4, rr = idx & 15;
        const float4 rf = s_rf[h][rr];
        const float* e1 = est1g + (size_t)(b * 8 + h) * 1024;
        const float* e2 = est2g + (size_t)(b * 8 + h) * 1024;
        float* arow = attn + ((size_t)(b * NHEADS + h) * NS + q * 16 + rr) * NT;
#pragma unroll
        for (int qq = 0; qq < 4; ++qq) {
            const int t0 = qq * 256 + lane * 4;
            const float4 a1 = *(const float4*)&e1[t0];
            const float4 a2 = *(const float4*)&e2[t0];
            float4 o;
            o.x = (a1.x >= rf.z) ? a1.x * rf.x : a2.x * rf.y;
            o.y = (a1.y >= rf.z) ? a1.y * rf.x : a2.y * rf.y;
            o.z = (a1.z >= rf.z) ? a1.z * rf.x : a2.z * rf.y;
            o.w = (a1.w >= rf.z) ? a1.w * rf.x : a2.w * rf.y;
            *(float4*)&arow[t0] = o;
        }
    }
}

extern "C" void kernel_launch(void* const* d_in, const int* in_sizes, int n_in,
                              void* d_out, int out_size, void* d_ws, size_t ws_size,
                              hipStream_t stream) {
    const float* src   = (const float*)d_in[0];
    const float* trg   = (const float*)d_in[1];
    const void*  smask = d_in[2];
    const void*  tmask = d_in[3];
    const float* Wsrc  = (const float*)d_in[4];
    const float* Wtrg  = (const float*)d_in[5];
    const float* asrc  = (const float*)d_in[6];
    const float* atrg  = (const float*)d_in[7];
    const float* Wout  = (const float*)d_in[8];

    float* out  = (float*)d_out;
    float* attn = out + (size_t)NB * NS * NE;

    char* wsb = (char*)d_ws;
    float* Vg    = (float*)(wsb + O_V);
    float* T1g   = (float*)(wsb + O_T1);
    float* T2g   = (float*)(wsb + O_T2);
    float* est1g = (float*)(wsb + O_EST1);
    float* est2g = (float*)(wsb + O_EST2);
    float4* rfg  = (float4*)(wsb + O_RF);
    unsigned short* Wt_t = (unsigned short*)(wsb + O_WTT);
    unsigned short* Wt_o = (unsigned short*)(wsb + O_WTO);
    float* c_src = (float*)(wsb + O_CSRC);
    float* c_trg = (float*)(wsb + O_CTRG);
    float* ssrc  = (float*)(wsb + O_SSRC);
    float* strg  = (float*)(wsb + O_STRG);
    int*   flag  = (int*)(wsb + O_FLAG);

    setup_kernel<<<35, 256, 0, stream>>>(
        (const unsigned*)tmask, Wsrc, Wtrg, Wout, asrc, atrg,
        c_src, c_trg, Wt_t, Wt_o, flag);

    mid_kernel<<<768, 256, 0, stream>>>(
        src, trg, c_src, c_trg, Wt_t, Vg, ssrc, strg);

    sortscan_kernel<<<NB * NHEADS, 256, 0, stream>>>(
        ssrc, strg, smask, tmask, flag, Vg, T1g, T2g, est1g, est2g, rfg);

    attnout_kernel<<<NB * (NS / 16), 256, 0, stream>>>(
        rfg, T1g, T2g, est1g, est2g, Wt_o, attn, out);
}

// Round 11
// 98.192 us; speedup vs baseline: 2.1146x; 2.1146x over previous
//
#include <hip/hip_runtime.h>
#include <hip/hip_bf16.h>
#include <math.h>

#define NB 8
#define NS 1024
#define NT 1024
#define NE 256
#define NHEADS 8
#define DH 32
#define LOG2E 1.4426950408889634f

typedef __attribute__((ext_vector_type(8))) short short8;
typedef __attribute__((ext_vector_type(8))) unsigned short ushort8;
typedef __attribute__((ext_vector_type(4))) float f32x4;

// ws layout (byte offsets)
#define O_VT    0u                        // ushort[8][8][32][1024] V^T swizzled
#define O_WTT   (8u<<20)                  // ushort[256*256] W_trg^T bf16 [n][k]
#define O_WTO   ((8u<<20)+131072u)        // ushort[256*256] W_out^T bf16 [n][k]
#define O_CSRC  ((8u<<20)+262144u)        // float[8*256]
#define O_CTRG  (O_CSRC+8192u)
#define O_SSRC  (O_CTRG+8192u)            // float[8192*8]
#define O_STRG  (O_SSRC+262144u)          // float[8192*8]
#define O_FLAG  (O_STRG+262144u)          // int

__device__ __forceinline__ unsigned short f2bf(float f) {
    __hip_bfloat16 h = __float2bfloat16(f);
    union { __hip_bfloat16 h; unsigned short u; } c; c.h = h;
    return c.u;
}
__device__ __forceinline__ float leaky(float v) {
    return (v >= 0.f) ? v : 0.2f * v;
}
// raw v_exp_f32 (= exp2); inputs pre-scaled by LOG2E
__device__ __forceinline__ float exp2_fast(float x) {
    float r;
    asm("v_exp_f32 %0, %1" : "=v"(r) : "v"(x));
    return r;
}

// ---------------------------------------------------------------------------
// K1 setup: bid0 = mask probe; bid1/2 = c_src/c_trg; bid3..34 = W transposes.
// ---------------------------------------------------------------------------
__global__ __launch_bounds__(256) void setup_kernel(
    const unsigned* __restrict__ tmask_dw, const float* __restrict__ Wsrc,
    const float* __restrict__ Wtrg, const float* __restrict__ Wout,
    const float* __restrict__ asrc, const float* __restrict__ atrg,
    float* __restrict__ c_src, float* __restrict__ c_trg,
    unsigned short* __restrict__ Wt_t, unsigned short* __restrict__ Wt_o,
    int* __restrict__ flag) {
    __shared__ __align__(16) char sm[16640];
    const int tid = threadIdx.x;
    const int bid = blockIdx.x;

    if (bid == 0) {
        __shared__ int s_ok;
        if (tid == 0) s_ok = 1;
        __syncthreads();
        for (int i = tid; i < 2048; i += 256)
            if (tmask_dw[i] > 1u) s_ok = 0;
        __syncthreads();
        if (tid == 0) *flag = s_ok;
    } else if (bid <= 2) {
        float* a_sh = (float*)sm;
        const float* W = (bid == 1) ? Wsrc : Wtrg;
        const float* a = (bid == 1) ? asrc : atrg;
        float* c = (bid == 1) ? c_src : c_trg;
        a_sh[tid] = a[tid];
        __syncthreads();
        const int e = tid;
        float ch[8];
#pragma unroll
        for (int h = 0; h < 8; ++h) ch[h] = 0.f;
        for (int i = 0; i < 64; ++i) {
            const float4 wv = *(const float4*)&W[(size_t)e * NE + i * 4];
            const int h = i >> 3, d0 = (i & 7) * 4;
            ch[h] += wv.x * a_sh[h * 32 + d0] + wv.y * a_sh[h * 32 + d0 + 1] +
                     wv.z * a_sh[h * 32 + d0 + 2] + wv.w * a_sh[h * 32 + d0 + 3];
        }
#pragma unroll
        for (int h = 0; h < 8; ++h) c[h * NE + e] = ch[h];
    } else {
        const int q = bid - 3;
        const float* W = (q >> 4) ? Wout : Wtrg;
        unsigned short* Wt = (q >> 4) ? Wt_o : Wt_t;
        const int tl = q & 15;
        const int k0 = (tl >> 2) * 64, n0 = (tl & 3) * 64;
        float* xs = (float*)sm;                   // [64][65]
#pragma unroll
        for (int it = 0; it < 4; ++it) {
            const int slot = it * 256 + tid;
            const int k = slot >> 4, c4 = slot & 15;
            const float4 v = *(const float4*)&W[(size_t)(k0 + k) * NE + n0 + c4 * 4];
            float* p = &xs[k * 65 + c4 * 4];
            p[0] = v.x; p[1] = v.y; p[2] = v.z; p[3] = v.w;
        }
        __syncthreads();
#pragma unroll
        for (int it = 0; it < 2; ++it) {
            const int slot = it * 256 + tid;
            const int n = slot >> 3, kc = slot & 7;
            ushort8 v;
#pragma unroll
            for (int e = 0; e < 8; ++e)
                v[e] = f2bf(xs[(kc * 8 + e) * 65 + n]);
            *(ushort8*)&Wt[(size_t)(n0 + n) * NE + k0 + kc * 8] = v;
        }
    }
}

// ---------------------------------------------------------------------------
// K2 mid: bid<256 -> V gemm (trg @ W_trg, bf16 MFMA) with LDS-transpose
// epilogue writing V^T swizzled to global Vt[b][h][d][t^((d&7)<<3)];
// bid>=256 -> score rows (src@c_src / trg@c_trg), exact f32.
// ---------------------------------------------------------------------------
__global__ __launch_bounds__(256) void mid_kernel(
    const float* __restrict__ src, const float* __restrict__ trg,
    const float* __restrict__ c_src, const float* __restrict__ c_trg,
    const unsigned short* __restrict__ Wt_t, unsigned short* __restrict__ Vt,
    float* __restrict__ ssrc, float* __restrict__ strg) {
    __shared__ __align__(16) char sm[49152];
    const int tid = threadIdx.x;
    const int bid = blockIdx.x;

    if (bid < 256) {
        unsigned short* As = (unsigned short*)sm;             // [64][256]
        unsigned short* ldsT = (unsigned short*)(sm + 32768); // [128][64]
        const int lane = tid & 63, w = tid >> 6;
        const int row0 = (bid >> 1) * 64;
        const int col0 = (bid & 1) * 128;

#pragma unroll
        for (int it = 0; it < 8; ++it) {
            const int gf = it * 256 + tid;
            const int row = gf >> 5, g3 = gf & 31;
            const float4 a = *(const float4*)&trg[(size_t)(row0 + row) * NE + g3 * 8];
            const float4 b = *(const float4*)&trg[(size_t)(row0 + row) * NE + g3 * 8 + 4];
            ushort8 v;
            v[0] = f2bf(a.x); v[1] = f2bf(a.y); v[2] = f2bf(a.z); v[3] = f2bf(a.w);
            v[4] = f2bf(b.x); v[5] = f2bf(b.y); v[6] = f2bf(b.z); v[7] = f2bf(b.w);
            *(ushort8*)&As[row * NE + ((g3 ^ (row & 7)) * 8)] = v;
        }
        __syncthreads();

        const int r = lane & 15, g = lane >> 4;
        short8 af[8];
#pragma unroll
        for (int kk = 0; kk < 8; ++kk)
            af[kk] = *(const short8*)&As[(w * 16 + r) * NE + (((kk * 4 + g) ^ (r & 7)) * 8)];

        f32x4 acc[8];
#pragma unroll
        for (int nt = 0; nt < 8; ++nt) acc[nt] = (f32x4){0.f, 0.f, 0.f, 0.f};
#pragma unroll
        for (int kk = 0; kk < 8; ++kk) {
#pragma unroll
            for (int nt = 0; nt < 8; ++nt) {
                const int col = col0 + nt * 16 + r;
                const short8 bf = *(const short8*)&Wt_t[(size_t)col * NE + kk * 32 + g * 8];
                acc[nt] = __builtin_amdgcn_mfma_f32_16x16x32_bf16(af[kk], bf, acc[nt], 0, 0, 0);
            }
        }
        __syncthreads();

        // transpose epilogue: ldsT[col][t ^ ((col&7)<<3)] = bf16(acc)
#pragma unroll
        for (int nt = 0; nt < 8; ++nt) {
            const int cl = nt * 16 + r;
            const int sw = (cl & 7) << 3;
#pragma unroll
            for (int j = 0; j < 4; ++j) {
                const int t = w * 16 + g * 4 + j;
                ldsT[cl * 64 + (t ^ sw)] = f2bf(acc[nt][j]);
            }
        }
        __syncthreads();

        const int b = row0 >> 10, t0 = row0 & 1023;
#pragma unroll
        for (int it = 0; it < 4; ++it) {
            const int slot = it * 256 + tid;
            const int cl = slot >> 3, ch = slot & 7;
            const int colg = col0 + cl;
            const int h = colg >> 5, d = colg & 31;
            *(ushort8*)&Vt[(((size_t)(b * 8 + h)) * 32 + d) * 1024 + t0 + ch * 8] =
                *(const ushort8*)&ldsT[cl * 64 + ch * 8];
        }
    } else {
        float* xs = (float*)sm;                  // [32][256]
        float* cs = (float*)(sm + 32768);        // [8][256]
        const int rowg0 = (bid - 256) * 32;
        const bool is_src = rowg0 < NB * NS;
        const float* X = is_src ? (src + (size_t)rowg0 * NE)
                                : (trg + (size_t)(rowg0 - NB * NS) * NE);
        const float* C = is_src ? c_src : c_trg;
        float* S = is_src ? (ssrc + (size_t)rowg0 * NHEADS)
                          : (strg + (size_t)(rowg0 - NB * NS) * NHEADS);

#pragma unroll
        for (int it = 0; it < 8; ++it) {
            const int slot = it * 256 + tid;
            const int row = slot >> 6, c4 = slot & 63;
            *(float4*)&xs[row * NE + c4 * 4] =
                *(const float4*)&X[(size_t)row * NE + c4 * 4];
            cs[slot] = C[slot];
        }
        __syncthreads();

        const int r = tid >> 3, h = tid & 7;
        float s = 0.f;
        for (int e = 0; e < NE; e += 4) {
            const float4 x = *(const float4*)&xs[r * NE + e];
            const float4 c = *(const float4*)&cs[h * NE + e];
            s += x.x * c.x + x.y * c.y + x.z * c.z + x.w * c.w;
        }
        S[(size_t)r * NHEADS + h] = s;
    }
}

// ---------------------------------------------------------------------------
// K3 fused: block = (b, 16-row stile), 512 threads = 8 waves, wave w = head w.
// passA (per wave, self-contained): exp2(leaky) -> bf16, unnormalized MFMA
//   vs Vt + row sums; inv via in-wave shfl reduction.
// barrier -> agg_sw (swizzled LDS bf16) -> barrier -> out-GEMM (small writes)
// -> attn stores LAST, unfenced to kernel end (no barrier after them, so no
// vmcnt(0) drain of the 512KB burst; streams overlap other blocks' compute).
// ---------------------------------------------------------------------------
__global__ __launch_bounds__(512) void fused_kernel(
    const float* __restrict__ ssrc, const float* __restrict__ strg,
    const void* __restrict__ smask, const void* __restrict__ tmask,
    const int* __restrict__ flag_p, const unsigned short* __restrict__ Vt,
    const unsigned short* __restrict__ Wt_o,
    float* __restrict__ attn, float* __restrict__ out) {
    const int blk = blockIdx.x;
    const int q = blk & 63;            // 16-row stile
    const int b = blk >> 6;
    const int tid = threadIdx.x;
    const int lane = tid & 63;
    const int w = tid >> 6;            // wave = head
    const int flag = *flag_p;

    __shared__ __align__(16) float s_sm[8][1024];            // 32 KB
    __shared__ __align__(16) unsigned short agg_sw[16 * 256]; // 8 KB
    __shared__ float s_inv[8][16];

    // stage all 8 heads' masked strg*LOG2E
    for (int t = tid; t < NT; t += 512) {
        const bool mv = flag ? (((const int*)tmask)[b * NT + t] != 0)
                             : (((const unsigned char*)tmask)[b * NT + t] != 0);
        const float4 s0 = *(const float4*)&strg[((size_t)b * NT + t) * 8];
        const float4 s1 = *(const float4*)&strg[((size_t)b * NT + t) * 8 + 4];
        const float sv[8] = {s0.x, s0.y, s0.z, s0.w, s1.x, s1.y, s1.z, s1.w};
#pragma unroll
        for (int h = 0; h < 8; ++h)
            s_sm[h][t] = mv ? sv[h] * LOG2E : -1e30f;
    }
    __syncthreads();

    const int r = lane & 15;
    const int g = lane >> 4;
    const int srow = q * 16 + r;
    const bool rowv = flag ? (((const int*)smask)[b * NS + srow] != 0)
                           : (((const unsigned char*)smask)[b * NS + srow] != 0);
    const int sw = (r & 7) << 3;
    const int h = w;
    const float ss2 = ssrc[((size_t)b * NS + srow) * NHEADS + h] * LOG2E;
    const unsigned short* vr0 = Vt + (size_t)(b * 8 + h) * 32768 + r * 1024;
    const unsigned short* vr1 = vr0 + 16 * 1024;

    // passA: unnormalized p -> row sum + MFMA
    f32x4 acc0 = {0.f, 0.f, 0.f, 0.f};
    f32x4 acc1 = {0.f, 0.f, 0.f, 0.f};
    float sum = 0.f;
#pragma unroll 4
    for (int c = 0; c < 32; ++c) {
        const int tb = c * 32 + g * 8;
        const short8 b0 = *(const short8*)&vr0[tb ^ sw];
        const short8 b1 = *(const short8*)&vr1[tb ^ sw];
        const float4 v0 = *(const float4*)&s_sm[h][tb];
        const float4 v1 = *(const float4*)&s_sm[h][tb + 4];
        const float vv[8] = {v0.x, v0.y, v0.z, v0.w, v1.x, v1.y, v1.z, v1.w};
        short8 pa;
#pragma unroll
        for (int e = 0; e < 8; ++e) {
            const float p = exp2_fast(leaky(ss2 + vv[e]));
            sum += p;
            pa[e] = (short)f2bf(p);
        }
        acc0 = __builtin_amdgcn_mfma_f32_16x16x32_bf16(pa, b0, acc0, 0, 0, 0);
        acc1 = __builtin_amdgcn_mfma_f32_16x16x32_bf16(pa, b1, acc1, 0, 0, 0);
    }
    sum += __shfl_xor(sum, 16);
    sum += __shfl_xor(sum, 32);
    const float inv = (rowv && sum > 0.f) ? 1.f / sum : 0.f;
    if (g == 0) s_inv[h][r] = inv;
    __syncthreads();   // s_inv ready (only small LDS traffic in flight)

    // agg epilogue -> swizzled LDS bf16 (C layout: col=lane&15, row=g*4+j)
#pragma unroll
    for (int j = 0; j < 4; ++j) {
        const int row = g * 4 + j;
        const float iv = s_inv[h][row];
        int col = h * 32 + r;
        agg_sw[row * 256 + ((((col >> 3) ^ (row & 7)) << 3) | (col & 7))] =
            f2bf(acc0[j] * iv);
        col += 16;
        agg_sw[row * 256 + ((((col >> 3) ^ (row & 7)) << 3) | (col & 7))] =
            f2bf(acc1[j] * iv);
    }
    __syncthreads();   // agg_sw ready

    // out-GEMM: 16 rows x 256 cols, K=256; wave w owns cols [w*32, w*32+32)
    f32x4 oacc[2];
#pragma unroll
    for (int nt = 0; nt < 2; ++nt) oacc[nt] = (f32x4){0.f, 0.f, 0.f, 0.f};
#pragma unroll
    for (int kk = 0; kk < 8; ++kk) {
        const short8 af = *(const short8*)&agg_sw[r * 256 + (((kk * 4 + g) ^ (r & 7)) * 8)];
#pragma unroll
        for (int nt = 0; nt < 2; ++nt) {
            const int col = w * 32 + nt * 16 + r;
            const short8 bf = *(const short8*)&Wt_o[(size_t)col * NE + kk * 32 + g * 8];
            oacc[nt] = __builtin_amdgcn_mfma_f32_16x16x32_bf16(af, bf, oacc[nt], 0, 0, 0);
        }
    }
#pragma unroll
    for (int nt = 0; nt < 2; ++nt) {
        const int col = w * 32 + nt * 16 + r;
#pragma unroll
        for (int j = 0; j < 4; ++j)
            out[((size_t)b * NS + q * 16 + g * 4 + j) * NE + col] = oacc[nt][j];
    }

    // attn stores LAST — wave-local (shfl for per-row ss/inv), no barrier after
    float* wbase = attn + ((size_t)(b * NHEADS + h) * NS + q * 16) * NT;
    for (int rr = 0; rr < 16; ++rr) {
        const float ssr = __shfl(ss2, rr);
        const float ivr = __shfl(inv, rr);
        float* arow = wbase + (size_t)rr * NT;
#pragma unroll
        for (int qq = 0; qq < 4; ++qq) {
            const int t0 = qq * 256 + lane * 4;
            const float4 sm4 = *(const float4*)&s_sm[h][t0];
            float4 o;
            o.x = exp2_fast(leaky(ssr + sm4.x)) * ivr;
            o.y = exp2_fast(leaky(ssr + sm4.y)) * ivr;
            o.z = exp2_fast(leaky(ssr + sm4.z)) * ivr;
            o.w = exp2_fast(leaky(ssr + sm4.w)) * ivr;
            *(float4*)&arow[t0] = o;
        }
    }
}

extern "C" void kernel_launch(void* const* d_in, const int* in_sizes, int n_in,
                              void* d_out, int out_size, void* d_ws, size_t ws_size,
                              hipStream_t stream) {
    const float* src   = (const float*)d_in[0];
    const float* trg   = (const float*)d_in[1];
    const void*  smask = d_in[2];
    const void*  tmask = d_in[3];
    const float* Wsrc  = (const float*)d_in[4];
    const float* Wtrg  = (const float*)d_in[5];
    const float* asrc  = (const float*)d_in[6];
    const float* atrg  = (const float*)d_in[7];
    const float* Wout  = (const float*)d_in[8];

    float* out  = (float*)d_out;
    float* attn = out + (size_t)NB * NS * NE;

    char* wsb = (char*)d_ws;
    unsigned short* Vt   = (unsigned short*)(wsb + O_VT);
    unsigned short* Wt_t = (unsigned short*)(wsb + O_WTT);
    unsigned short* Wt_o = (unsigned short*)(wsb + O_WTO);
    float* c_src = (float*)(wsb + O_CSRC);
    float* c_trg = (float*)(wsb + O_CTRG);
    float* ssrc  = (float*)(wsb + O_SSRC);
    float* strg  = (float*)(wsb + O_STRG);
    int*   flag  = (int*)(wsb + O_FLAG);

    setup_kernel<<<35, 256, 0, stream>>>(
        (const unsigned*)tmask, Wsrc, Wtrg, Wout, asrc, atrg,
        c_src, c_trg, Wt_t, Wt_o, flag);

    mid_kernel<<<768, 256, 0, stream>>>(
        src, trg, c_src, c_trg, Wt_t, Vt, ssrc, strg);

    fused_kernel<<<NB * (NS / 16), 512, 0, stream>>>(
        ssrc, strg, smask, tmask, flag, Vt, Wt_o, attn, out);
}